// Round 17
// baseline (162.814 us; speedup 1.0000x reference)
//
#include <hip/hip_runtime.h>
#include <math.h>

// CrossAttention B=2, Sq=Sk=2048, H=16, Hkv=4, D=64, fp32 io.
// R27: halved image traffic AT high wave count. Counter model: main reads
// ~279MB of tile images via L2/L3 in 40us (~7TB/s, invisible in FETCH),
// occupancy 28%, no pipe >25% -> waves parked on load-return. Matrix:
// R20 halved traffic @8 waves/CU (54us, starved); R24 full traffic @20
// waves/CU (40us). Untested cell: halved traffic + high waves. 512-thread
// blocks (8 waves) = 2 heads of one hkv group sharing every staged tile;
// per-wave body BYTE-IDENTICAL to R26 (16 rows of one head); grid 512+32;
// bounds(512,6) cap 85 >> VGPR 44 (no spill), 3 blocks/CU -> ~24 waves/CU.
// Fixup re-indexed for 8 waves. Prep, mask-in-data, literal-buffer unroll,
// EBIAS-in-acc-init all unchanged. Pre-commit: main >=42us -> revert R26,
// declare ceiling.

typedef __bf16 bf16x4 __attribute__((ext_vector_type(4)));
typedef __bf16 bf16x8 __attribute__((ext_vector_type(8)));
typedef float floatx4 __attribute__((ext_vector_type(4)));
typedef short shortx4 __attribute__((ext_vector_type(4)));

#define SQ 2048
#define SK 2048
#define H_ 16
#define HKV 4
#define D_ 64
#define QT 64
#define KT 64
#define KVROW 512           // floats per (b,s) slot: 2*HKV*D
#define NEGV (-10000.0f)
#define QSCL 0.18033688f    // 0.125 * log2(e)
#define EBIAS 17.3123405f   // fixed softmax shift (exp2 space)

static __device__ __forceinline__ floatx4 mfma16(bf16x4 a, bf16x4 b, floatx4 c) {
#if __has_builtin(__builtin_amdgcn_mfma_f32_16x16x16bf16_1k)
    return __builtin_amdgcn_mfma_f32_16x16x16bf16_1k(
        __builtin_bit_cast(shortx4, a), __builtin_bit_cast(shortx4, b), c, 0, 0, 0);
#else
    floatx4 d;
    asm("v_mfma_f32_16x16x16_bf16 %0, %1, %2, %3"
        : "=v"(d) : "v"(a), "v"(b), "v"(c));
    return d;
#endif
}

static __device__ __forceinline__ void gload16(const void* g, void* l) {
    __builtin_amdgcn_global_load_lds(
        (const __attribute__((address_space(1))) unsigned int*)g,
        (__attribute__((address_space(3))) unsigned int*)l, 16, 0, 0);
}

// ===== prep: fp32 KV -> bf16 swizzled tile images (32KB stride) ==========
// image: [K 8KB swizzled][V^T 8KB swizzled, padded rows zeroed]
//        @16384: bf16 m01[64] (pad-mask 0/1 row)
__global__ __launch_bounds__(256)
void prep_kernel(const float* __restrict__ kv, const int* __restrict__ mask,
                 char* __restrict__ imgs)
{
    __shared__ alignas(16) __bf16 Vl[64][64];
    const int tid = threadIdx.x;
    const int bid = (int)blockIdx.x;            // ((b*4+hkv)*32 + kt)
    const int kt = bid & 31, hkv = (bid >> 5) & 3, b = bid >> 7;
    const float* kvb = kv + ((size_t)b * SK + kt * KT) * KVROW + hkv * D_;
    const float* vvb = kvb + HKV * D_;
    char* img = imgs + ((size_t)bid << 15);

    const int r  = tid >> 2;       // key (K part) / key (V read)
    const int gg = tid & 3;        // 16-float group

    // ---- K image: row r (key), d in [gg*16, gg*16+16) ----
    {
        const float* p = kvb + (size_t)r * KVROW + gg * 16;
        float4 f0 = *(const float4*)(p + 0), f1 = *(const float4*)(p + 4);
        float4 f2 = *(const float4*)(p + 8), f3 = *(const float4*)(p + 12);
        bf16x8 c0 = { (__bf16)f0.x, (__bf16)f0.y, (__bf16)f0.z, (__bf16)f0.w,
                      (__bf16)f1.x, (__bf16)f1.y, (__bf16)f1.z, (__bf16)f1.w };
        bf16x8 c1 = { (__bf16)f2.x, (__bf16)f2.y, (__bf16)f2.z, (__bf16)f2.w,
                      (__bf16)f3.x, (__bf16)f3.y, (__bf16)f3.z, (__bf16)f3.w };
        const int xo = (r & 7) << 4;
        *(bf16x8*)(img + r * 128 + (((gg * 2 + 0) * 16) ^ xo)) = c0;
        *(bf16x8*)(img + r * 128 + (((gg * 2 + 1) * 16) ^ xo)) = c1;
    }
    // ---- V: read row r (key), transpose into Vl[d][key]; zero padded keys
    {
        const float mker = mask[b * SK + kt * KT + r] ? 1.0f : 0.0f;
        const float* p = vvb + (size_t)r * KVROW + gg * 16;
        float4 f0 = *(const float4*)(p + 0), f1 = *(const float4*)(p + 4);
        float4 f2 = *(const float4*)(p + 8), f3 = *(const float4*)(p + 12);
        float t[16] = { f0.x, f0.y, f0.z, f0.w, f1.x, f1.y, f1.z, f1.w,
                        f2.x, f2.y, f2.z, f2.w, f3.x, f3.y, f3.z, f3.w };
#pragma unroll
        for (int j = 0; j < 16; ++j)
            Vl[gg * 16 + j][r] = (__bf16)(t[j] * mker);
    }
    __syncthreads();
    // ---- V image: chunk c = 16B of row rr (=d), keys [g*8, g*8+8) ----
#pragma unroll
    for (int i = 0; i < 2; ++i) {
        const int c = tid * 2 + i, rr = c >> 3, g = c & 7;
        bf16x8 v = *(const bf16x8*)&Vl[rr][g * 8];
        *(bf16x8*)(img + 8192 + rr * 128 + ((g * 16) ^ ((rr & 7) << 4))) = v;
    }
    // ---- bf16 0/1 mask row @16384 ----
    if (tid < 64) {
        const int m = mask[b * SK + kt * KT + tid];
        *((__bf16*)(img + 16384) + tid) = (__bf16)(m ? 1.0f : 0.0f);
    }
}

// ===== main attention ====================================================
__global__ __launch_bounds__(512, 6)
void attn_kernel(const float* __restrict__ q,
                 const float* __restrict__ kv,
                 const int* __restrict__ mask,
                 float* __restrict__ out,
                 float* __restrict__ ws)
{
    __shared__ alignas(16) union {
        struct {                       // exactly 32768 B
            __bf16 K[2][KT * D_];      // 8KB per buf, swizzled image
            __bf16 V[2][D_ * KT];      // 8KB per buf, transposed+swizzled
        } m;
        struct {                       // fixup role only (blocks 0..31)
            float fpart[8][64];
            float fw[8][64];
            int   s_first;
        } f;
    } sh;

    const int tid  = threadIdx.x;
    const int wave = tid >> 6;         // 0..7
    const int lane = tid & 63;
    const int col  = lane & 15;
    const int quad = lane >> 4;

    if (blockIdx.x < 32) {
        // ================= fixup role: rows R < first_kept[b] ===============
        const int bh = (int)blockIdx.x;
        const int b = bh >> 4, h = bh & 15, hkv = h >> 2;
        if (tid == 0) sh.f.s_first = SK;
        __syncthreads();
        int local = SK;
        for (int s = tid; s < SK; s += 512)
            if (mask[b * SK + s]) local = min(local, s);
        atomicMin(&sh.f.s_first, local);
        __syncthreads();
        const int nfirst = sh.f.s_first;
        if (nfirst == 0) return;

        const float* kvb = kv + (size_t)b * SK * KVROW + hkv * D_;
        const float* vvb = kvb + HKV * D_;
        {
            float a0=0,a1=0,a2=0,a3=0,a4=0,a5=0,a6=0,a7=0;
            const int s0 = wave * 256;
            for (int s = s0; s < s0 + 256; s += 8) {
                a0 += vvb[(size_t)(s+0)*KVROW + lane];
                a1 += vvb[(size_t)(s+1)*KVROW + lane];
                a2 += vvb[(size_t)(s+2)*KVROW + lane];
                a3 += vvb[(size_t)(s+3)*KVROW + lane];
                a4 += vvb[(size_t)(s+4)*KVROW + lane];
                a5 += vvb[(size_t)(s+5)*KVROW + lane];
                a6 += vvb[(size_t)(s+6)*KVROW + lane];
                a7 += vvb[(size_t)(s+7)*KVROW + lane];
            }
            sh.f.fpart[wave][lane] = ((a0+a1)+(a2+a3)) + ((a4+a5)+(a6+a7));
        }
        __syncthreads();
        float vtotal = 0.f;
#pragma unroll
        for (int w = 0; w < 8; ++w) vtotal += sh.f.fpart[w][lane];

        for (int R = wave; R < nfirst; R += 8) {
            const float* qrow = q + (((size_t)b * SQ + R) * H_ + h) * D_;
            float mymax = -3.4e38f;
            for (int s = lane; s <= R; s += 64) {
                const float* kp = kvb + (size_t)s * KVROW;
                float dt = 0.f;
                for (int d = 0; d < D_; ++d) dt += qrow[d] * kp[d];
                mymax = fmaxf(mymax, dt * 0.125f + NEGV);
            }
#pragma unroll
            for (int off = 32; off >= 1; off >>= 1)
                mymax = fmaxf(mymax, __shfl_xor(mymax, off, 64));
            const float M = (R < SK - 1) ? fmaxf(mymax, NEGV) : mymax;
            float lsum = 0.f, oacc = 0.f, pref = 0.f;
            for (int s0 = 0; s0 <= R; s0 += 64) {
                int s = s0 + lane;
                float w = 0.f;
                if (s <= R) {
                    const float* kp = kvb + (size_t)s * KVROW;
                    float dt = 0.f;
                    for (int d = 0; d < D_; ++d) dt += qrow[d] * kp[d];
                    w = __expf(dt * 0.125f + NEGV - M);
                    lsum += w;
                }
                sh.f.fw[wave][lane] = w;   // wave-private, in-order
                const int nk = (R - s0 + 1 < 64) ? (R - s0 + 1) : 64;
                for (int j = 0; j < nk; ++j) {
                    const float vj = vvb[(size_t)(s0 + j) * KVROW + lane];
                    oacc += sh.f.fw[wave][j] * vj;
                    pref += vj;
                }
            }
#pragma unroll
            for (int off = 32; off >= 1; off >>= 1)
                lsum += __shfl_xor(lsum, off, 64);
            const float wn   = __expf(NEGV - M);
            const float ltot = lsum + wn * (float)(SK - 1 - R);
            out[(((size_t)b * SQ + R) * H_ + h) * D_ + lane] =
                (oacc + wn * (vtotal - pref)) / ltot;
        }
        return;
    }

    // ========== main role: 8 waves, 2 heads/block (same hkv), snake =======
    const int id = (int)blockIdx.x - 32;
    const int combo = id & 15;            // b(1) x hkv(2) x pair(1)
    const int y  = id >> 4;               // 0..31
    const int kg = y >> 3, jj = y & 7;    // quad {31-j, j, 23-j, 8+j}: 66 tiles
    const int qt = (kg == 0) ? 31 - jj : (kg == 1) ? jj : (kg == 2) ? 23 - jj : 8 + jj;
    const int b = combo >> 3, hkv = (combo >> 1) & 3, hp = combo & 1;
    const int h = hkv * 4 + hp * 2 + (wave & 1);   // this wave's head
    const int qw = qt * QT + (wave >> 1) * 16;     // this wave's 16 rows

    const char* timg0 = (const char*)ws + ((size_t)((b * 4 + hkv) * 32) << 15);

    // ---- Q B-fragments (swapped QK), pre-scaled into exp2 space ----
    bf16x8 aq[2];
    {
        const int row = qw + col;
        const float* qp = q + (((size_t)b * SQ + row) * H_ + h) * D_ + quad * 8;
#pragma unroll
        for (int kc = 0; kc < 2; ++kc) {
            const float* p = qp + kc * 32;
#pragma unroll
            for (int j = 0; j < 8; ++j) aq[kc][j] = (__bf16)(p[j] * QSCL);
        }
    }

    floatx4 o[4];
    floatx4 l_acc = (floatx4){0.f, 0.f, 0.f, 0.f};
#pragma unroll
    for (int dj = 0; dj < 4; ++dj) o[dj] = (floatx4){0.f, 0.f, 0.f, 0.f};

    const int c7 = col & 7;
    const int xo = c7 << 4;

    auto gstage = [&](int kt, const int bb) {
        const char* img = timg0 + ((size_t)kt << 15);
        // 8 waves x 1KB each cover the 8KB K image and 8KB V image
        gload16(img + wave * 1024 + lane * 16,
                (char*)&sh.m.K[bb][0] + wave * 1024);
        gload16(img + 8192 + wave * 1024 + lane * 16,
                (char*)&sh.m.V[bb][0] + wave * 1024);
    };

    // per-tile mask row -> registers (plain per-lane loads, broadcast)
    auto loadmk = [&](int kt, bf16x4* mk) {
        const char* mrow = timg0 + ((size_t)kt << 15) + 16384;
#pragma unroll
        for (int kj = 0; kj < 4; ++kj)
            mk[kj] = *(const bf16x4*)(mrow + kj * 32 + quad * 8);
    };

    auto tile_body = [&](const int CUR, const int kt, const bf16x4* mk) {
        // QK^T swapped: c[kj]=S^T block, lane holds S[qrow=col][key16=quad*4+r]
        // acc init = -EBIAS, so p = exp2(c) directly (no subtract).
        const char* Kb = (const char*)&sh.m.K[CUR][0];
        floatx4 c[4];
        __builtin_amdgcn_s_setprio(1);
#pragma unroll
        for (int kj = 0; kj < 4; ++kj) {
            c[kj] = (floatx4){-EBIAS, -EBIAS, -EBIAS, -EBIAS};
#pragma unroll
            for (int kc = 0; kc < 2; ++kc) {
                bf16x8 ak = *(const bf16x8*)(Kb + (kj * 16 + col) * 128
                                                + ((((kc * 4 + quad) ^ c7) << 4)));
                c[kj] = __builtin_amdgcn_mfma_f32_16x16x32_bf16(ak, aq[kc], c[kj], 0, 0, 0);
            }
        }
        __builtin_amdgcn_s_setprio(0);

        // exp2, lane-local; P packed in regs. Pad mask lives in DATA (V rows
        // zeroed + m01 l-operand). Causal select only on the diagonal tile.
        bf16x4 pk[4];
        if (kt == qt) {
            const int tcl = (wave >> 1) * 16 + col - quad * 4;
#pragma unroll
            for (int kj = 0; kj < 4; ++kj)
#pragma unroll
                for (int r = 0; r < 4; ++r) {
                    float p = __builtin_amdgcn_exp2f(c[kj][r]);
                    pk[kj][r] = (__bf16)((kj * 16 + r <= tcl) ? p : 0.f);
                }
        } else {
#pragma unroll
            for (int kj = 0; kj < 4; ++kj)
#pragma unroll
                for (int r = 0; r < 4; ++r)
                    pk[kj][r] = (__bf16)__builtin_amdgcn_exp2f(c[kj][r]);
        }

        // l via mask-row MFMA + PV from swizzled V image
        const char* Vb = (const char*)&sh.m.V[CUR][0];
        __builtin_amdgcn_s_setprio(1);
#pragma unroll
        for (int kj = 0; kj < 4; ++kj)
            l_acc = mfma16(pk[kj], mk[kj], l_acc);
#pragma unroll
        for (int dj = 0; dj < 4; ++dj)
#pragma unroll
            for (int kj = 0; kj < 4; ++kj) {
                bf16x4 bv = *(const bf16x4*)(Vb + (dj * 16 + col) * 128
                                                + ((kj * 32 + quad * 8) ^ xo));
                o[dj] = mfma16(pk[kj], bv, o[dj]);
            }
        __builtin_amdgcn_s_setprio(0);
    };

    const int k1 = qt + 1;
    gstage(0, 0);
    int kt = 0;
    for (;;) {
        __syncthreads();                       // buf0 resident (vmcnt drained)
        bf16x4 mkA[4];
        loadmk(kt, mkA);                       // oldest VMEM: wait != vmcnt(0)
        if (kt + 1 < k1) gstage(kt + 1, 1);    // newest: stays in flight
        tile_body(0, kt, mkA);
        if (++kt == k1) break;
        __syncthreads();                       // buf1 resident
        bf16x4 mkB[4];
        loadmk(kt, mkB);
        if (kt + 1 < k1) gstage(kt + 1, 0);
        tile_body(1, kt, mkB);
        if (++kt == k1) break;
    }

    // ---- epilogue: normalize + store; l==0 rows written by fixup role ----
#pragma unroll
    for (int r = 0; r < 4; ++r) {
        const float l = l_acc[r];
        if (l > 0.f) {
            const float inv = 1.0f / l;
            const int row = qw + quad * 4 + r;
            float* op = out + (((size_t)b * SQ + row) * H_ + h) * D_ + col;
#pragma unroll
            for (int dj = 0; dj < 4; ++dj)
                op[dj * 16] = o[dj][r] * inv;
        }
    }
}

extern "C" void kernel_launch(void* const* d_in, const int* in_sizes, int n_in,
                              void* d_out, int out_size, void* d_ws, size_t ws_size,
                              hipStream_t stream) {
    const float* q   = (const float*)d_in[0];
    const float* kv  = (const float*)d_in[1];
    const int* mask  = (const int*)d_in[2];
    float* out       = (float*)d_out;
    prep_kernel<<<dim3(256), 256, 0, stream>>>(kv, mask, (char*)d_ws);
    attn_kernel<<<dim3(32 + 512), 512, 0, stream>>>(q, kv, mask, out, (float*)d_ws);
}

// Round 18
// 107.607 us; speedup vs baseline: 1.5130x; 1.5130x over previous
//
#include <hip/hip_runtime.h>
#include <math.h>

// CrossAttention B=2, Sq=Sk=2048, H=16, Hkv=4, D=64, fp32 io.
// R28 = R24 verbatim (best verified: 108.0us harness, main ~40.5us).
// R27 (8-wave head-sharing) regressed to 97us main -> head-sharing is
// conclusively negative (R20: 54us @4-wave, R27: 97us @8-wave); the
// barrier-delimited per-tile chain x tiles-per-block is the binding
// structure and R24's config (4-wave blocks, 1056 blocks, 66-tile snake)
// is its measured optimum. 17-round ledger: wins = P-roundtrip removal
// (R13), prepped swizzled images + global_load_lds staging (R17, -29%),
// dispatch consolidation (R19), literal-buffer unroll + EBIAS-in-init
// (R22), mask-in-data (R24). Nulls/regressions: LDS-traffic halving,
// split-K (x2), launch-bounds occupancy (spill wall at unified-RF cap),
// explicit dbuf, free-run waves, head-sharing (x2), coop prep fusion
// (XCD coherence), 5-block residency. Remaining harness time is ~63us
// fixed (workspace re-poison fill ~44us @76% HBM + launch gaps) +
// prep 4.4 + main ~40.5 (latency-structural floor: no pipe >35%).

typedef __bf16 bf16x4 __attribute__((ext_vector_type(4)));
typedef __bf16 bf16x8 __attribute__((ext_vector_type(8)));
typedef float floatx4 __attribute__((ext_vector_type(4)));
typedef short shortx4 __attribute__((ext_vector_type(4)));

#define SQ 2048
#define SK 2048
#define H_ 16
#define HKV 4
#define D_ 64
#define QT 64
#define KT 64
#define KVROW 512           // floats per (b,s) slot: 2*HKV*D
#define NEGV (-10000.0f)
#define QSCL 0.18033688f    // 0.125 * log2(e)
#define EBIAS 17.3123405f   // fixed softmax shift (exp2 space)

static __device__ __forceinline__ floatx4 mfma16(bf16x4 a, bf16x4 b, floatx4 c) {
#if __has_builtin(__builtin_amdgcn_mfma_f32_16x16x16bf16_1k)
    return __builtin_amdgcn_mfma_f32_16x16x16bf16_1k(
        __builtin_bit_cast(shortx4, a), __builtin_bit_cast(shortx4, b), c, 0, 0, 0);
#else
    floatx4 d;
    asm("v_mfma_f32_16x16x16_bf16 %0, %1, %2, %3"
        : "=v"(d) : "v"(a), "v"(b), "v"(c));
    return d;
#endif
}

static __device__ __forceinline__ void gload16(const void* g, void* l) {
    __builtin_amdgcn_global_load_lds(
        (const __attribute__((address_space(1))) unsigned int*)g,
        (__attribute__((address_space(3))) unsigned int*)l, 16, 0, 0);
}

// ===== prep: fp32 KV -> bf16 swizzled tile images (32KB stride) ==========
// image: [K 8KB swizzled][V^T 8KB swizzled, padded rows zeroed]
//        @16384: bf16 m01[64] (pad-mask 0/1 row)
__global__ __launch_bounds__(256)
void prep_kernel(const float* __restrict__ kv, const int* __restrict__ mask,
                 char* __restrict__ imgs)
{
    __shared__ alignas(16) __bf16 Vl[64][64];
    const int tid = threadIdx.x;
    const int bid = (int)blockIdx.x;            // ((b*4+hkv)*32 + kt)
    const int kt = bid & 31, hkv = (bid >> 5) & 3, b = bid >> 7;
    const float* kvb = kv + ((size_t)b * SK + kt * KT) * KVROW + hkv * D_;
    const float* vvb = kvb + HKV * D_;
    char* img = imgs + ((size_t)bid << 15);

    const int r  = tid >> 2;       // key (K part) / key (V read)
    const int gg = tid & 3;        // 16-float group

    // ---- K image: row r (key), d in [gg*16, gg*16+16) ----
    {
        const float* p = kvb + (size_t)r * KVROW + gg * 16;
        float4 f0 = *(const float4*)(p + 0), f1 = *(const float4*)(p + 4);
        float4 f2 = *(const float4*)(p + 8), f3 = *(const float4*)(p + 12);
        bf16x8 c0 = { (__bf16)f0.x, (__bf16)f0.y, (__bf16)f0.z, (__bf16)f0.w,
                      (__bf16)f1.x, (__bf16)f1.y, (__bf16)f1.z, (__bf16)f1.w };
        bf16x8 c1 = { (__bf16)f2.x, (__bf16)f2.y, (__bf16)f2.z, (__bf16)f2.w,
                      (__bf16)f3.x, (__bf16)f3.y, (__bf16)f3.z, (__bf16)f3.w };
        const int xo = (r & 7) << 4;
        *(bf16x8*)(img + r * 128 + (((gg * 2 + 0) * 16) ^ xo)) = c0;
        *(bf16x8*)(img + r * 128 + (((gg * 2 + 1) * 16) ^ xo)) = c1;
    }
    // ---- V: read row r (key), transpose into Vl[d][key]; zero padded keys
    {
        const float mker = mask[b * SK + kt * KT + r] ? 1.0f : 0.0f;
        const float* p = vvb + (size_t)r * KVROW + gg * 16;
        float4 f0 = *(const float4*)(p + 0), f1 = *(const float4*)(p + 4);
        float4 f2 = *(const float4*)(p + 8), f3 = *(const float4*)(p + 12);
        float t[16] = { f0.x, f0.y, f0.z, f0.w, f1.x, f1.y, f1.z, f1.w,
                        f2.x, f2.y, f2.z, f2.w, f3.x, f3.y, f3.z, f3.w };
#pragma unroll
        for (int j = 0; j < 16; ++j)
            Vl[gg * 16 + j][r] = (__bf16)(t[j] * mker);
    }
    __syncthreads();
    // ---- V image: chunk c = 16B of row rr (=d), keys [g*8, g*8+8) ----
#pragma unroll
    for (int i = 0; i < 2; ++i) {
        const int c = tid * 2 + i, rr = c >> 3, g = c & 7;
        bf16x8 v = *(const bf16x8*)&Vl[rr][g * 8];
        *(bf16x8*)(img + 8192 + rr * 128 + ((g * 16) ^ ((rr & 7) << 4))) = v;
    }
    // ---- bf16 0/1 mask row @16384 ----
    if (tid < 64) {
        const int m = mask[b * SK + kt * KT + tid];
        *((__bf16*)(img + 16384) + tid) = (__bf16)(m ? 1.0f : 0.0f);
    }
}

// ===== main attention ====================================================
__global__ __launch_bounds__(256, 4)
void attn_kernel(const float* __restrict__ q,
                 const float* __restrict__ kv,
                 const int* __restrict__ mask,
                 float* __restrict__ out,
                 float* __restrict__ ws)
{
    __shared__ alignas(16) union {
        struct {                       // exactly 32768 B
            __bf16 K[2][KT * D_];      // 8KB per buf, swizzled image
            __bf16 V[2][D_ * KT];      // 8KB per buf, transposed+swizzled
        } m;
        struct {                       // fixup role only (blocks 0..31)
            float fpart[4][64];
            float fw[4][64];
            int   s_first;
        } f;
    } sh;

    const int tid  = threadIdx.x;
    const int wave = tid >> 6;
    const int lane = tid & 63;
    const int col  = lane & 15;
    const int quad = lane >> 4;

    if (blockIdx.x < 32) {
        // ================= fixup role: rows R < first_kept[b] ===============
        const int bh = (int)blockIdx.x;
        const int b = bh >> 4, h = bh & 15, hkv = h >> 2;
        if (tid == 0) sh.f.s_first = SK;
        __syncthreads();
        int local = SK;
        for (int s = tid; s < SK; s += 256)
            if (mask[b * SK + s]) local = min(local, s);
        atomicMin(&sh.f.s_first, local);
        __syncthreads();
        const int nfirst = sh.f.s_first;
        if (nfirst == 0) return;

        const float* kvb = kv + (size_t)b * SK * KVROW + hkv * D_;
        const float* vvb = kvb + HKV * D_;
        {
            float a0=0,a1=0,a2=0,a3=0,a4=0,a5=0,a6=0,a7=0;
            const int s0 = wave * 512;
            for (int s = s0; s < s0 + 512; s += 8) {
                a0 += vvb[(size_t)(s+0)*KVROW + lane];
                a1 += vvb[(size_t)(s+1)*KVROW + lane];
                a2 += vvb[(size_t)(s+2)*KVROW + lane];
                a3 += vvb[(size_t)(s+3)*KVROW + lane];
                a4 += vvb[(size_t)(s+4)*KVROW + lane];
                a5 += vvb[(size_t)(s+5)*KVROW + lane];
                a6 += vvb[(size_t)(s+6)*KVROW + lane];
                a7 += vvb[(size_t)(s+7)*KVROW + lane];
            }
            sh.f.fpart[wave][lane] = ((a0+a1)+(a2+a3)) + ((a4+a5)+(a6+a7));
        }
        __syncthreads();
        const float vtotal = sh.f.fpart[0][lane] + sh.f.fpart[1][lane]
                           + sh.f.fpart[2][lane] + sh.f.fpart[3][lane];

        for (int R = wave; R < nfirst; R += 4) {
            const float* qrow = q + (((size_t)b * SQ + R) * H_ + h) * D_;
            float mymax = -3.4e38f;
            for (int s = lane; s <= R; s += 64) {
                const float* kp = kvb + (size_t)s * KVROW;
                float dt = 0.f;
                for (int d = 0; d < D_; ++d) dt += qrow[d] * kp[d];
                mymax = fmaxf(mymax, dt * 0.125f + NEGV);
            }
#pragma unroll
            for (int off = 32; off >= 1; off >>= 1)
                mymax = fmaxf(mymax, __shfl_xor(mymax, off, 64));
            const float M = (R < SK - 1) ? fmaxf(mymax, NEGV) : mymax;
            float lsum = 0.f, oacc = 0.f, pref = 0.f;
            for (int s0 = 0; s0 <= R; s0 += 64) {
                int s = s0 + lane;
                float w = 0.f;
                if (s <= R) {
                    const float* kp = kvb + (size_t)s * KVROW;
                    float dt = 0.f;
                    for (int d = 0; d < D_; ++d) dt += qrow[d] * kp[d];
                    w = __expf(dt * 0.125f + NEGV - M);
                    lsum += w;
                }
                sh.f.fw[wave][lane] = w;   // wave-private, in-order
                const int nk = (R - s0 + 1 < 64) ? (R - s0 + 1) : 64;
                for (int j = 0; j < nk; ++j) {
                    const float vj = vvb[(size_t)(s0 + j) * KVROW + lane];
                    oacc += sh.f.fw[wave][j] * vj;
                    pref += vj;
                }
            }
#pragma unroll
            for (int off = 32; off >= 1; off >>= 1)
                lsum += __shfl_xor(lsum, off, 64);
            const float wn   = __expf(NEGV - M);
            const float ltot = lsum + wn * (float)(SK - 1 - R);
            out[(((size_t)b * SQ + R) * H_ + h) * D_ + lane] =
                (oacc + wn * (vtotal - pref)) / ltot;
        }
        return;
    }

    // ================= main attention role (snake schedule) ================
    const int id = (int)blockIdx.x - 32;
    const int bh = id & 31;
    const int y  = id >> 5;               // 0..31
    const int kg = y >> 3, jj = y & 7;    // quad {31-j, j, 23-j, 8+j}: 66 tiles
    const int qt = (kg == 0) ? 31 - jj : (kg == 1) ? jj : (kg == 2) ? 23 - jj : 8 + jj;
    const int b = bh >> 4, h = bh & 15, hkv = h >> 2;
    const int qw = qt * QT + wave * 16;

    const char* timg0 = (const char*)ws + ((size_t)((b * 4 + hkv) * 32) << 15);

    // ---- Q B-fragments (swapped QK), pre-scaled into exp2 space ----
    bf16x8 aq[2];
    {
        const int row = qw + col;
        const float* qp = q + (((size_t)b * SQ + row) * H_ + h) * D_ + quad * 8;
#pragma unroll
        for (int kc = 0; kc < 2; ++kc) {
            const float* p = qp + kc * 32;
#pragma unroll
            for (int j = 0; j < 8; ++j) aq[kc][j] = (__bf16)(p[j] * QSCL);
        }
    }

    floatx4 o[4];
    floatx4 l_acc = (floatx4){0.f, 0.f, 0.f, 0.f};
#pragma unroll
    for (int dj = 0; dj < 4; ++dj) o[dj] = (floatx4){0.f, 0.f, 0.f, 0.f};

    const int c7 = col & 7;
    const int xo = c7 << 4;

    auto gstage = [&](int kt, const int bb) {
        const char* img = timg0 + ((size_t)kt << 15);
        const char* gsK = img + wave * 1024 + lane * 16;
        const char* gsV = img + 8192 + wave * 1024 + lane * 16;
        char* ldK = (char*)&sh.m.K[bb][0] + wave * 1024;   // wave-uniform base
        char* ldV = (char*)&sh.m.V[bb][0] + wave * 1024;
        gload16(gsK,        ldK);
        gload16(gsK + 4096, ldK + 4096);
        gload16(gsV,        ldV);
        gload16(gsV + 4096, ldV + 4096);
    };

    // per-tile mask row -> registers (plain per-lane loads, broadcast)
    auto loadmk = [&](int kt, bf16x4* mk) {
        const char* mrow = timg0 + ((size_t)kt << 15) + 16384;
#pragma unroll
        for (int kj = 0; kj < 4; ++kj)
            mk[kj] = *(const bf16x4*)(mrow + kj * 32 + quad * 8);
    };

    auto tile_body = [&](const int CUR, const int kt, const bf16x4* mk) {
        // QK^T swapped: c[kj]=S^T block, lane holds S[qrow=col][key16=quad*4+r]
        // acc init = -EBIAS, so p = exp2(c) directly (no subtract).
        const char* Kb = (const char*)&sh.m.K[CUR][0];
        floatx4 c[4];
        __builtin_amdgcn_s_setprio(1);
#pragma unroll
        for (int kj = 0; kj < 4; ++kj) {
            c[kj] = (floatx4){-EBIAS, -EBIAS, -EBIAS, -EBIAS};
#pragma unroll
            for (int kc = 0; kc < 2; ++kc) {
                bf16x8 ak = *(const bf16x8*)(Kb + (kj * 16 + col) * 128
                                                + ((((kc * 4 + quad) ^ c7) << 4)));
                c[kj] = __builtin_amdgcn_mfma_f32_16x16x32_bf16(ak, aq[kc], c[kj], 0, 0, 0);
            }
        }
        __builtin_amdgcn_s_setprio(0);

        // exp2, lane-local; P packed in regs. Pad mask lives in DATA (V rows
        // zeroed + m01 l-operand). Causal select only on the diagonal tile.
        bf16x4 pk[4];
        if (kt == qt) {
            const int tcl = wave * 16 + col - quad * 4;
#pragma unroll
            for (int kj = 0; kj < 4; ++kj)
#pragma unroll
                for (int r = 0; r < 4; ++r) {
                    float p = __builtin_amdgcn_exp2f(c[kj][r]);
                    pk[kj][r] = (__bf16)((kj * 16 + r <= tcl) ? p : 0.f);
                }
        } else {
#pragma unroll
            for (int kj = 0; kj < 4; ++kj)
#pragma unroll
                for (int r = 0; r < 4; ++r)
                    pk[kj][r] = (__bf16)__builtin_amdgcn_exp2f(c[kj][r]);
        }

        // l via mask-row MFMA + PV from swizzled V image
        const char* Vb = (const char*)&sh.m.V[CUR][0];
        __builtin_amdgcn_s_setprio(1);
#pragma unroll
        for (int kj = 0; kj < 4; ++kj)
            l_acc = mfma16(pk[kj], mk[kj], l_acc);
#pragma unroll
        for (int dj = 0; dj < 4; ++dj)
#pragma unroll
            for (int kj = 0; kj < 4; ++kj) {
                bf16x4 bv = *(const bf16x4*)(Vb + (dj * 16 + col) * 128
                                                + ((kj * 32 + quad * 8) ^ xo));
                o[dj] = mfma16(pk[kj], bv, o[dj]);
            }
        __builtin_amdgcn_s_setprio(0);
    };

    const int k1 = qt + 1;
    gstage(0, 0);
    int kt = 0;
    for (;;) {
        __syncthreads();                       // buf0 resident (vmcnt drained)
        bf16x4 mkA[4];
        loadmk(kt, mkA);                       // oldest VMEM: wait != vmcnt(0)
        if (kt + 1 < k1) gstage(kt + 1, 1);    // newest: stays in flight
        tile_body(0, kt, mkA);
        if (++kt == k1) break;
        __syncthreads();                       // buf1 resident
        bf16x4 mkB[4];
        loadmk(kt, mkB);
        if (kt + 1 < k1) gstage(kt + 1, 0);
        tile_body(1, kt, mkB);
        if (++kt == k1) break;
    }

    // ---- epilogue: normalize + store; l==0 rows written by fixup role ----
#pragma unroll
    for (int r = 0; r < 4; ++r) {
        const float l = l_acc[r];
        if (l > 0.f) {
            const float inv = 1.0f / l;
            const int row = qw + quad * 4 + r;
            float* op = out + (((size_t)b * SQ + row) * H_ + h) * D_ + col;
#pragma unroll
            for (int dj = 0; dj < 4; ++dj)
                op[dj * 16] = o[dj][r] * inv;
        }
    }
}

extern "C" void kernel_launch(void* const* d_in, const int* in_sizes, int n_in,
                              void* d_out, int out_size, void* d_ws, size_t ws_size,
                              hipStream_t stream) {
    const float* q   = (const float*)d_in[0];
    const float* kv  = (const float*)d_in[1];
    const int* mask  = (const int*)d_in[2];
    float* out       = (float*)d_out;
    prep_kernel<<<dim3(256), 256, 0, stream>>>(kv, mask, (char*)d_ws);
    attn_kernel<<<dim3(32 + 1024), 256, 0, stream>>>(q, kv, mask, out, (float*)d_ws);
}